// Round 16
// baseline (1380.633 us; speedup 1.0000x reference)
//
#include <hip/hip_runtime.h>

#define B_    32
#define L_    4096
#define DM    128
#define DI    256
#define DS_   16
#define RANK  8
#define NL    4
#define M_    (B_*L_)   // 131072 rows
#define NC    64        // scan chunks along L
#define CL    (L_/NC)   // 64 steps per chunk

typedef __attribute__((ext_vector_type(8))) short short8;
typedef __attribute__((ext_vector_type(4))) float floatx4;
typedef __attribute__((ext_vector_type(2))) float float2v;   // targets v_pk_*_f32

__device__ __forceinline__ float b2f(unsigned short u) {
    return __uint_as_float(((unsigned)u) << 16);
}
__device__ __forceinline__ unsigned short f2b(float f) {
    unsigned u = __float_as_uint(f);
    unsigned r = u + 0x7fffu + ((u >> 16) & 1u);   // RNE
    return (unsigned short)(r >> 16);
}
__device__ __forceinline__ float fast_sig(float v) {   // 1/(1+e^-v) via v_rcp_f32
    return __builtin_amdgcn_rcpf(1.f + __expf(-v));
}

// ---------------- D0: detect input dtype (bf16 vs fp32) ----------------
__global__ __launch_bounds__(256) void k_detect(const unsigned short* __restrict__ x,
                                                int* __restrict__ flag) {
    __shared__ int cnt;
    if (threadIdx.x == 0) cnt = 0;
    __syncthreads();
    int ok = 0;
    for (int i = 0; i < 4; ++i) {
        unsigned short u = x[threadIdx.x * 4 + i];
        int e = (u >> 7) & 0xFF;
        if ((u & 0x7FFF) == 0 || (e >= 100 && e <= 150)) ok++;
    }
    atomicAdd(&cnt, ok);
    __syncthreads();
    if (threadIdx.x == 0) *flag = (cnt >= 800) ? 1 : 0;   // 1 = inputs are bf16
}

// ---------------- D1: conversions ----------------
struct CvtSeg { const void* src; float* dst; int n; };
struct CvtPack { CvtSeg seg[11]; };
__global__ __launch_bounds__(256) void k_cvt_params(CvtPack p, const int* __restrict__ flag) {
    int s = blockIdx.y;
    int i = blockIdx.x * 256 + threadIdx.x;
    if (i >= p.seg[s].n) return;
    p.seg[s].dst[i] = (*flag) ? b2f(((const unsigned short*)p.seg[s].src)[i])
                              : ((const float*)p.seg[s].src)[i];
}
__global__ __launch_bounds__(256) void k_cvt16(const void* __restrict__ src,
                                               unsigned short* __restrict__ dst,
                                               int n, const int* __restrict__ flag) {
    int i = blockIdx.x * 256 + threadIdx.x;
    if (i >= n) return;
    if (*flag) dst[i] = ((const unsigned short*)src)[i];
    else       dst[i] = f2b(((const float*)src)[i]);
}
// pad x_proj_w [NL][40][256] -> bf16 [NL][48][256], rows 40..47 zero
__global__ __launch_bounds__(256) void k_xpw48(const void* __restrict__ src,
                                               unsigned short* __restrict__ dst,
                                               const int* __restrict__ flag) {
    int i = blockIdx.x * 256 + threadIdx.x;   // < NL*48*256
    int col = i & 255, rowl = (i >> 8) % 48, layer = i / (48*256);
    unsigned short v = 0;
    if (rowl < 40) {
        int si = (layer*40 + rowl)*256 + col;
        v = (*flag) ? ((const unsigned short*)src)[si] : f2b(((const float*)src)[si]);
    }
    dst[i] = v;
}

// ---------------- K0: h = x * input_proj_w + input_proj_b (reads raw x) ----------------
__global__ __launch_bounds__(256) void k_init(const void* __restrict__ xraw,
                                              const int* __restrict__ flag,
                                              const float* __restrict__ ipw,
                                              const float* __restrict__ ipb,
                                              float* __restrict__ h, int base) {
    int idx = blockIdx.x * 256 + threadIdx.x;     // < Mc*DM
    int bl = idx >> 7, d = idx & 127;
    float x = (*flag) ? b2f(((const unsigned short*)xraw)[base + bl])
                      : ((const float*)xraw)[base + bl];
    h[idx] = x * ipw[d] + ipb[d];
}

// ---------------- K1: xz = h @ in_w^T (MFMA bf16) -> bf16 xb|zb (layer 0 only) ----------------
__global__ __launch_bounds__(256) void k_gemm_in(const float* __restrict__ h,
                                                 const unsigned short* __restrict__ w, // bf16 [512][128]
                                                 unsigned short* __restrict__ xb,
                                                 unsigned short* __restrict__ zb) {
    __shared__ unsigned short lA[64][136];
    __shared__ unsigned short lW[256][40];
    int tid = threadIdx.x;
    int lane = tid & 63, wv = tid >> 6;
    int ln = lane & 15, qd = lane >> 4;
    int r0 = blockIdx.x * 64;
    int n0 = blockIdx.y * 256;

    { // stage A (fp32 h -> bf16 LDS)
        int r = tid >> 2;
        int c0 = (tid & 3) * 32;
        const float4* src = (const float4*)(h + (size_t)(r0 + r) * DM + c0);
        for (int j = 0; j < 8; ++j) {
            float4 v = src[j];
            lA[r][c0 + j*4 + 0] = f2b(v.x);
            lA[r][c0 + j*4 + 1] = f2b(v.y);
            lA[r][c0 + j*4 + 2] = f2b(v.z);
            lA[r][c0 + j*4 + 3] = f2b(v.w);
        }
    }

    floatx4 acc[16];
    for (int i = 0; i < 16; ++i) acc[i] = (floatx4)0.f;

    for (int kc = 0; kc < 4; ++kc) {
        __syncthreads();
        { // stage W chunk: 256 n x 32 k (bf16)
            int n = tid;
            const uint4* src = (const uint4*)(w + (size_t)(n0 + n) * DM + kc * 32);
            uint4 a = src[0], b = src[1], c = src[2], d = src[3];
            *(uint4*)&lW[n][0]  = a;
            *(uint4*)&lW[n][8]  = b;
            *(uint4*)&lW[n][16] = c;
            *(uint4*)&lW[n][24] = d;
        }
        __syncthreads();
        short8 af = *(const short8*)&lA[wv*16 + ln][kc*32 + qd*8];
        for (int nt = 0; nt < 16; ++nt) {
            short8 bf = *(const short8*)&lW[nt*16 + ln][qd*8];
            acc[nt] = __builtin_amdgcn_mfma_f32_16x16x32_bf16(af, bf, acc[nt], 0, 0, 0);
        }
    }

    for (int nt = 0; nt < 16; ++nt)
        for (int rg = 0; rg < 4; ++rg) {
            size_t gr = (size_t)(r0 + wv*16 + qd*4 + rg);
            int gc = nt*16 + ln;
            unsigned short v = f2b(acc[nt][rg]);
            if (blockIdx.y == 0) xb[gr*DI + gc] = v;
            else                 zb[gr*DI + gc] = v;
        }
}

// A[s] = -(s+1) structure check (reference: A_log = log(1..16) tiled)
__device__ __forceinline__ bool a_is_integer_ladder(const float* A) {
    bool f = true;
    #pragma unroll
    for (int s = 0; s < DS_; ++s)
        f = f && (fabsf(A[s] + (float)(s+1)) < 0.01f * (float)(s+1));
    return f;
}

// unpack 8 bf16 (uint4) -> 8 floats
__device__ __forceinline__ void unpack8(uint4 p, float* f) {
    f[0] = b2f((unsigned short)(p.x & 0xffff)); f[1] = b2f((unsigned short)(p.x >> 16));
    f[2] = b2f((unsigned short)(p.y & 0xffff)); f[3] = b2f((unsigned short)(p.y >> 16));
    f[4] = b2f((unsigned short)(p.z & 0xffff)); f[5] = b2f((unsigned short)(p.z >> 16));
    f[6] = b2f((unsigned short)(p.w & 0xffff)); f[7] = b2f((unsigned short)(p.w >> 16));
}
// pack 16 floats -> 2 uint4 of bf16
__device__ __forceinline__ void pack16(const float* f, uint4* o) {
    unsigned v[8];
    #pragma unroll
    for (int j = 0; j < 8; ++j)
        v[j] = (unsigned)f2b(f[2*j]) | ((unsigned)f2b(f[2*j+1]) << 16);
    o[0] = make_uint4(v[0], v[1], v[2], v[3]);
    o[1] = make_uint4(v[4], v[5], v[6], v[7]);
}

// ---------------- K2: conv4+SiLU, x_proj (MFMA), dt+softplus, fused chunk scan emitting y_loc & S ----------------
// One block = 64 rows = one scan chunk (CL==64). Outputs: xcg, Cg, y_loc (ylg), S (Sg), Pbuf/Hbuf.
// B never goes to HBM (LDS-only); pass 3 uses y_l = y_loc_l + C_l·(exp(A*S_l) ⊙ h_start).
__global__ __launch_bounds__(256) void k_xprojc(const unsigned short* __restrict__ xb,
                                                const float* __restrict__ cw,   // [DI][4]
                                                const float* __restrict__ cbp,  // [DI]
                                                const unsigned short* __restrict__ w48, // bf16 [48][256]
                                                const float* __restrict__ dtw,  // fp32 [DI][8]
                                                const float* __restrict__ dtb,  // fp32 [DI]
                                                const float* __restrict__ alog, // fp32 [DI][DS_]
                                                unsigned short* __restrict__ xcg, // bf16 out
                                                unsigned short* __restrict__ ylg, // bf16 out (y_loc)
                                                unsigned short* __restrict__ Sg,  // bf16 out (prefix dt)
                                                unsigned short* __restrict__ Cg,  // bf16 out
                                                unsigned short* __restrict__ Pbuf,  // bf16
                                                unsigned short* __restrict__ Hbuf) {// bf16
    __shared__ unsigned short lA[64][264];
    __shared__ unsigned short lW[48][40];
    __shared__ float ldbl[64][8];
    __shared__ float lBs[64][DS_];           // bf16-rounded B rows (LDS only)
    __shared__ float lCs[64][DS_];           // bf16-rounded C rows (for y_loc dot)
    int tid = threadIdx.x;
    int lane = tid & 63, wv = tid >> 6;
    int ln = lane & 15, qd = lane >> 4;
    int r0 = blockIdx.x * 64;
    int l0 = r0 & (L_ - 1);                  // tiles never straddle batches
    int bidx = r0 >> 12;                     // r0 / L_
    int kidx = l0 >> 6;                      // chunk index (CL==64)

    { // causal conv + SiLU: column c across 64 rows -> lA (bf16) + xcg global
        int c = tid;
        float w0 = cw[c*4+0], w1 = cw[c*4+1], w2 = cw[c*4+2], w3 = cw[c*4+3];
        float bias = cbp[c];
        float x0 = (l0 >= 3) ? b2f(xb[(size_t)(r0-3)*DI + c]) : 0.f;
        float x1 = (l0 >= 2) ? b2f(xb[(size_t)(r0-2)*DI + c]) : 0.f;
        float x2 = (l0 >= 1) ? b2f(xb[(size_t)(r0-1)*DI + c]) : 0.f;
        for (int r = 0; r < 64; ++r) {
            float xcur = b2f(xb[(size_t)(r0+r)*DI + c]);
            float v = w0*x0 + w1*x1 + w2*x2 + w3*xcur + bias;
            float s = v * fast_sig(v);
            unsigned short sb = f2b(s);
            lA[r][c] = sb;
            xcg[(size_t)(r0+r)*DI + c] = sb;
            x0 = x1; x1 = x2; x2 = xcur;
        }
    }

    floatx4 acc[3];
    for (int i = 0; i < 3; ++i) acc[i] = (floatx4)0.f;

    for (int kc = 0; kc < 8; ++kc) {
        __syncthreads();
        if (tid < 192) {   // stage W chunk: 48 n x 32 k bf16
            int n = tid >> 2, q = tid & 3;
            *(uint4*)&lW[n][q*8] = *(const uint4*)(w48 + (size_t)n*DI + kc*32 + q*8);
        }
        __syncthreads();
        short8 af = *(const short8*)&lA[wv*16 + ln][kc*32 + qd*8];
        for (int nt = 0; nt < 3; ++nt) {
            short8 bf = *(const short8*)&lW[nt*16 + ln][qd*8];
            acc[nt] = __builtin_amdgcn_mfma_f32_16x16x32_bf16(af, bf, acc[nt], 0, 0, 0);
        }
    }

    for (int nt = 0; nt < 3; ++nt)
        for (int rg = 0; rg < 4; ++rg) {
            int rloc = wv*16 + qd*4 + rg;
            size_t row = (size_t)(r0 + rloc);
            int n = nt*16 + ln;
            float v = acc[nt][rg];
            if (n < 8)       ldbl[rloc][n] = v;
            else if (n < 24) {
                lBs[rloc][n-8] = b2f(f2b(v));        // bf16-rounded, LDS only
            }
            else if (n < 40) {
                unsigned short cv = f2b(v);
                Cg[row*DS_ + (n-24)] = cv;
                lCs[rloc][n-24] = b2f(cv);           // same rounding as ygate's read
            }
        }
    __syncthreads();

    { // dt_proj + softplus + fused chunk-local scan; emit y_loc, S per row
        int c = tid;
        float2v w2v[4];
        #pragma unroll
        for (int j = 0; j < 4; ++j) { w2v[j].x = dtw[c*8 + 2*j]; w2v[j].y = dtw[c*8 + 2*j + 1]; }
        float bias = dtb[c];
        float A[DS_];
        #pragma unroll
        for (int j = 0; j < 4; ++j) {
            float4 a4 = *(const float4*)(alog + c*DS_ + j*4);
            A[j*4+0] = -__expf(a4.x); A[j*4+1] = -__expf(a4.y);
            A[j*4+2] = -__expf(a4.z); A[j*4+3] = -__expf(a4.w);
        }
        float P[DS_], hh[DS_];
        if (a_is_integer_ladder(A)) {        // fast path: packed pairs, P from S
            float2v h2[8];
            #pragma unroll
            for (int j = 0; j < 8; ++j) h2[j] = (float2v)0.f;
            float S = 0.f;
            for (int r = 0; r < 64; ++r) {
                float2v a2; a2.x = bias; a2.y = 0.f;
                const float2v* d2 = (const float2v*)&ldbl[r][0];
                #pragma unroll
                for (int j = 0; j < 4; ++j) a2 = a2 + d2[j]*w2v[j];
                float a = a2.x + a2.y;
                float sp = (a > 20.f) ? a : __logf(1.f + __expf(a));
                float dtv = b2f(f2b(sp));    // rounded (stored implicitly via S/y_loc)
                float du = dtv * b2f(lA[r][c]);
                float Bl[DS_], Cl[DS_];
                *(float4*)&Bl[0]  = *(const float4*)&lBs[r][0];
                *(float4*)&Bl[4]  = *(const float4*)&lBs[r][4];
                *(float4*)&Bl[8]  = *(const float4*)&lBs[r][8];
                *(float4*)&Bl[12] = *(const float4*)&lBs[r][12];
                *(float4*)&Cl[0]  = *(const float4*)&lCs[r][0];
                *(float4*)&Cl[4]  = *(const float4*)&lCs[r][4];
                *(float4*)&Cl[8]  = *(const float4*)&lCs[r][8];
                *(float4*)&Cl[12] = *(const float4*)&lCs[r][12];
                float E = __expf(-dtv);
                float E2 = E * E;
                float2v ep[8];
                ep[0].x = E; ep[0].y = E2;
                float2v E22; E22.x = E2; E22.y = E2;
                #pragma unroll
                for (int j = 1; j < 8; ++j) ep[j] = ep[j-1] * E22;
                float2v du2; du2.x = du; du2.y = du;
                float2v yv = (float2v)0.f;
                #pragma unroll
                for (int j = 0; j < 8; ++j) {
                    float2v bj; bj.x = Bl[2*j]; bj.y = Bl[2*j+1];
                    float2v cj; cj.x = Cl[2*j]; cj.y = Cl[2*j+1];
                    h2[j] = ep[j]*h2[j] + du2*bj;
                    yv = yv + h2[j]*cj;
                }
                S += dtv;
                size_t row = (size_t)(r0 + r);
                ylg[row*DI + c] = f2b(yv.x + yv.y);
                Sg[row*DI + c]  = f2b(S);
            }
            #pragma unroll
            for (int s = 0; s < DS_; ++s) P[s] = __expf(-(float)(s+1) * S);
            #pragma unroll
            for (int j = 0; j < 8; ++j) { hh[2*j] = h2[j].x; hh[2*j+1] = h2[j].y; }
        } else {                              // generic path
            #pragma unroll
            for (int s = 0; s < DS_; ++s) { hh[s] = 0.f; P[s] = 1.f; }
            float S = 0.f;
            for (int r = 0; r < 64; ++r) {
                float a = bias;
                #pragma unroll
                for (int j = 0; j < 8; ++j) a += ldbl[r][j] * ((j & 1) ? w2v[j>>1].y : w2v[j>>1].x);
                float sp = (a > 20.f) ? a : __logf(1.f + __expf(a));
                float dtv = b2f(f2b(sp));
                float du = dtv * b2f(lA[r][c]);
                float Bl[DS_], Cl[DS_];
                *(float4*)&Bl[0]  = *(const float4*)&lBs[r][0];
                *(float4*)&Bl[4]  = *(const float4*)&lBs[r][4];
                *(float4*)&Bl[8]  = *(const float4*)&lBs[r][8];
                *(float4*)&Bl[12] = *(const float4*)&lBs[r][12];
                *(float4*)&Cl[0]  = *(const float4*)&lCs[r][0];
                *(float4*)&Cl[4]  = *(const float4*)&lCs[r][4];
                *(float4*)&Cl[8]  = *(const float4*)&lCs[r][8];
                *(float4*)&Cl[12] = *(const float4*)&lCs[r][12];
                float yv = 0.f;
                #pragma unroll
                for (int s = 0; s < DS_; ++s) {
                    float e = __expf(dtv * A[s]);
                    hh[s] = e*hh[s] + du*Bl[s];
                    yv += hh[s]*Cl[s];
                    P[s] *= e;
                }
                S += dtv;
                size_t row = (size_t)(r0 + r);
                ylg[row*DI + c] = f2b(yv);
                Sg[row*DI + c]  = f2b(S);
            }
        }
        uint4 op[2], oh[2];
        pack16(P, op);
        pack16(hh, oh);
        uint4* pp = (uint4*)(Pbuf + (((size_t)bidx*NC + kidx)*DI + c)*DS_);
        uint4* ph = (uint4*)(Hbuf + (((size_t)bidx*NC + kidx)*DI + c)*DS_);
        pp[0] = op[0]; pp[1] = op[1];
        ph[0] = oh[0]; ph[1] = oh[1];
    }
}

// ---------------- K3b: propagate carries across chunks (bf16 P/H, fp32 carry) ----------------
__global__ __launch_bounds__(256) void k_scan2(const unsigned short* __restrict__ Pbuf,
                                               unsigned short* __restrict__ Hbuf,
                                               int cb) {
    int t = blockIdx.x * 256 + threadIdx.x;
    if (t >= cb * DI * DS_) return;
    int b  = t / (DI * DS_);
    int cs = t % (DI * DS_);
    float H = 0.f;
    for (int k = 0; k < NC; ++k) {
        size_t idx = ((size_t)b * NC + k) * (DI * DS_) + cs;
        float P  = b2f(Pbuf[idx]);
        float he = b2f(Hbuf[idx]);
        Hbuf[idx] = f2b(H);
        H = P * H + he;
    }
}

// ---------------- K3c: dependency-free finalize: y = y_loc + C·(exp(A*S)⊙h_start); gate -> bf16 ----------------
__global__ __launch_bounds__(256) void k_ygate(const unsigned short* __restrict__ ylg, // bf16 y_loc
                                               const unsigned short* __restrict__ Sg,  // bf16 prefix dt
                                               const unsigned short* __restrict__ xcg, // bf16
                                               const unsigned short* __restrict__ Cg,  // bf16
                                               const float* __restrict__ alog,
                                               const unsigned short* __restrict__ Hbuf,// bf16 h_start
                                               const unsigned short* __restrict__ zb,  // bf16
                                               const float* __restrict__ Dp,
                                               unsigned short* __restrict__ yg) {      // bf16 out
    __shared__ float lC[CL*DS_];
    int c = threadIdx.x;
    int k = blockIdx.x, b = blockIdx.y;
    size_t row0 = (size_t)b * L_ + (size_t)k * CL;
    if (c < 128) {   // stage C: 1024 bf16 = 128 uint4 -> fp32 LDS
        uint4 p = ((const uint4*)(Cg + row0*DS_))[c];
        float f[8]; unpack8(p, f);
        *(float4*)&lC[c*8]     = make_float4(f[0], f[1], f[2], f[3]);
        *(float4*)&lC[c*8 + 4] = make_float4(f[4], f[5], f[6], f[7]);
    }
    float A[DS_];
    #pragma unroll
    for (int j = 0; j < 4; ++j) {
        float4 a4 = *(const float4*)(alog + c*DS_ + j*4);
        A[j*4+0] = -__expf(a4.x); A[j*4+1] = -__expf(a4.y);
        A[j*4+2] = -__expf(a4.z); A[j*4+3] = -__expf(a4.w);
    }
    float Dc = Dp[c];
    float h0[DS_];
    {
        const uint4* ph = (const uint4*)(Hbuf + (((size_t)b*NC + k)*DI + c)*DS_);
        uint4 p0 = ph[0], p1 = ph[1];
        unpack8(p0, &h0[0]);
        unpack8(p1, &h0[8]);
    }
    __syncthreads();
    const unsigned short* pyl = ylg + row0*DI + c;
    const unsigned short* pS  = Sg  + row0*DI + c;
    const unsigned short* pxc = xcg + row0*DI + c;
    const unsigned short* pz  = zb  + row0*DI + c;
    unsigned short* py        = yg  + row0*DI + c;

    if (a_is_integer_ladder(A)) {          // fast path: decay = E^(s+1), E = exp(-S)
        float2v hp[8];
        #pragma unroll
        for (int j = 0; j < 8; ++j) { hp[j].x = h0[2*j]; hp[j].y = h0[2*j+1]; }
        for (int l = 0; l < CL; ++l) {
            float yl  = b2f(pyl[(size_t)l*DI]);
            float S   = b2f(pS [(size_t)l*DI]);
            float xcc = b2f(pxc[(size_t)l*DI]);
            float zc  = b2f(pz [(size_t)l*DI]);
            float Cl[DS_];
            *(float4*)&Cl[0]  = *(const float4*)&lC[l*DS_ + 0];
            *(float4*)&Cl[4]  = *(const float4*)&lC[l*DS_ + 4];
            *(float4*)&Cl[8]  = *(const float4*)&lC[l*DS_ + 8];
            *(float4*)&Cl[12] = *(const float4*)&lC[l*DS_ + 12];
            float E = __expf(-S);
            float E2 = E * E;
            float2v ep[8];
            ep[0].x = E; ep[0].y = E2;
            float2v E22; E22.x = E2; E22.y = E2;
            #pragma unroll
            for (int j = 1; j < 8; ++j) ep[j] = ep[j-1] * E22;
            float2v y2 = (float2v)0.f;
            #pragma unroll
            for (int j = 0; j < 8; ++j) {
                float2v cj; cj.x = Cl[2*j]; cj.y = Cl[2*j+1];
                float2v t = ep[j] * hp[j];
                y2 = y2 + t * cj;
            }
            float y = yl + y2.x + y2.y;
            py[(size_t)l*DI] = f2b((y + Dc*xcc) * (zc * fast_sig(zc)));
        }
    } else {                                // generic path: decay[s] = exp(A[s]*S)
        for (int l = 0; l < CL; ++l) {
            float yl  = b2f(pyl[(size_t)l*DI]);
            float S   = b2f(pS [(size_t)l*DI]);
            float xcc = b2f(pxc[(size_t)l*DI]);
            float zc  = b2f(pz [(size_t)l*DI]);
            float Cl[DS_];
            *(float4*)&Cl[0]  = *(const float4*)&lC[l*DS_ + 0];
            *(float4*)&Cl[4]  = *(const float4*)&lC[l*DS_ + 4];
            *(float4*)&Cl[8]  = *(const float4*)&lC[l*DS_ + 8];
            *(float4*)&Cl[12] = *(const float4*)&lC[l*DS_ + 12];
            float y = yl;
            #pragma unroll
            for (int s = 0; s < DS_; ++s)
                y += Cl[s] * __expf(A[s]*S) * h0[s];
            py[(size_t)l*DI] = f2b((y + Dc*xcc) * (zc * fast_sig(zc)));
        }
    }
}

// ---------------- K4a: fused h += yg @ ow^T ; xz = h_new @ in_w_next^T ----------------
// yg aliases xb (row-tile-local: each block reads only the rows it later overwrites).
__global__ __launch_bounds__(256) void k_gemm_oi(const unsigned short* yg,              // bf16 [Mc][256]
                                                 const unsigned short* __restrict__ wo, // bf16 [128][256]
                                                 const unsigned short* __restrict__ wi, // bf16 [512][128]
                                                 float* __restrict__ h,
                                                 unsigned short* xb,
                                                 unsigned short* __restrict__ zb) {
    __shared__ unsigned short lA[64*264];   // phase-1 A (stride 264); phase-3 overlays (stride 136)
    __shared__ unsigned short lW[256*40];
    int tid = threadIdx.x;
    int lane = tid & 63, wv = tid >> 6;
    int ln = lane & 15, qd = lane >> 4;
    int r0 = blockIdx.x * 64;

    // ---- phase 1: delta = yg @ wo^T (64x128, K=256) ----
    for (int j = 0; j < 8; ++j) {
        int idx = tid + j*256;
        int r = idx >> 5, q = idx & 31;
        *(uint4*)&lA[r*264 + q*8] = *(const uint4*)(yg + (size_t)(r0 + r)*DI + q*8);
    }
    floatx4 acc1[8];
    for (int i = 0; i < 8; ++i) acc1[i] = (floatx4)0.f;
    for (int kc = 0; kc < 8; ++kc) {
        __syncthreads();
        {
            int n = tid >> 1, half = tid & 1;
            const uint4* src = (const uint4*)(wo + (size_t)n*DI + kc*32 + half*16);
            uint4 a = src[0], b4 = src[1];
            *(uint4*)&lW[n*40 + half*16]     = a;
            *(uint4*)&lW[n*40 + half*16 + 8] = b4;
        }
        __syncthreads();
        short8 af = *(const short8*)&lA[(wv*16 + ln)*264 + kc*32 + qd*8];
        for (int nt = 0; nt < 8; ++nt) {
            short8 bf = *(const short8*)&lW[(nt*16 + ln)*40 + qd*8];
            acc1[nt] = __builtin_amdgcn_mfma_f32_16x16x32_bf16(af, bf, acc1[nt], 0, 0, 0);
        }
    }
    __syncthreads();   // all phase-1 LDS reads complete before overlaying lA

    // ---- phase 2: h_new = h_old + delta -> global fp32 + bf16 into lA (stride 136) ----
    for (int nt = 0; nt < 8; ++nt)
        for (int rg = 0; rg < 4; ++rg) {
            int rloc = wv*16 + qd*4 + rg;
            size_t gr = (size_t)(r0 + rloc);
            int gc = nt*16 + ln;
            float hv = h[gr*DM + gc] + acc1[nt][rg];
            h[gr*DM + gc] = hv;
            lA[rloc*136 + gc] = f2b(hv);
        }
    __syncthreads();

    // ---- phase 3: xz = h_new @ wi^T (64x512, K=128), two 256-col halves ----
    for (int n0 = 0; n0 < 2; ++n0) {
        floatx4 acc2[16];
        for (int i = 0; i < 16; ++i) acc2[i] = (floatx4)0.f;
        for (int kc = 0; kc < 4; ++kc) {
            __syncthreads();
            {
                int n = tid;
                const uint4* src = (const uint4*)(wi + (size_t)(n0*256 + n)*DM + kc*32);
                uint4 a = src[0], b = src[1], c = src[2], d = src[3];
                *(uint4*)&lW[n*40 + 0]  = a;
                *(uint4*)&lW[n*40 + 8]  = b;
                *(uint4*)&lW[n*40 + 16] = c;
                *(uint4*)&lW[n*40 + 24] = d;
            }
            __syncthreads();
            short8 af = *(const short8*)&lA[(wv*16 + ln)*136 + kc*32 + qd*8];
            for (int nt = 0; nt < 16; ++nt) {
                short8 bf = *(const short8*)&lW[(nt*16 + ln)*40 + qd*8];
                acc2[nt] = __builtin_amdgcn_mfma_f32_16x16x32_bf16(af, bf, acc2[nt], 0, 0, 0);
            }
        }
        unsigned short* dst = (n0 == 0) ? xb : zb;
        for (int nt = 0; nt < 16; ++nt)
            for (int rg = 0; rg < 4; ++rg) {
                size_t gr = (size_t)(r0 + wv*16 + qd*4 + rg);
                int gc = nt*16 + ln;
                dst[gr*DI + gc] = f2b(acc2[nt][rg]);
            }
    }
}

// ---------------- K4b: h += yg @ ow^T (last layer) ----------------
__global__ __launch_bounds__(256) void k_gemm_out(const unsigned short* __restrict__ yg, // bf16 [Mc][256]
                                                  const unsigned short* __restrict__ w,  // bf16 [128][256]
                                                  float* __restrict__ h) {
    __shared__ unsigned short lA[64][264];
    __shared__ unsigned short lW[128][40];
    int tid = threadIdx.x;
    int lane = tid & 63, wv = tid >> 6;
    int ln = lane & 15, qd = lane >> 4;
    int r0 = blockIdx.x * 64;

    for (int j = 0; j < 8; ++j) {
        int idx = tid + j*256;
        int r = idx >> 5, q = idx & 31;
        *(uint4*)&lA[r][q*8] = *(const uint4*)(yg + (size_t)(r0 + r)*DI + q*8);
    }

    floatx4 acc[8];
    for (int i = 0; i < 8; ++i) acc[i] = (floatx4)0.f;

    for (int kc = 0; kc < 8; ++kc) {
        __syncthreads();
        {
            int n = tid >> 1, half = tid & 1;
            const uint4* src = (const uint4*)(w + (size_t)n*DI + kc*32 + half*16);
            uint4 a = src[0], b4 = src[1];
            *(uint4*)&lW[n][half*16]     = a;
            *(uint4*)&lW[n][half*16 + 8] = b4;
        }
        __syncthreads();
        short8 af = *(const short8*)&lA[wv*16 + ln][kc*32 + qd*8];
        for (int nt = 0; nt < 8; ++nt) {
            short8 bf = *(const short8*)&lW[nt*16 + ln][qd*8];
            acc[nt] = __builtin_amdgcn_mfma_f32_16x16x32_bf16(af, bf, acc[nt], 0, 0, 0);
        }
    }

    for (int nt = 0; nt < 8; ++nt)
        for (int rg = 0; rg < 4; ++rg) {
            size_t gr = (size_t)(r0 + wv*16 + qd*4 + rg);
            int gc = nt*16 + ln;
            h[gr*DM + gc] += acc[nt][rg];
        }
}

// ---------------- K5: RMSNorm(last step) + output projection (fp32 out) ----------------
__global__ __launch_bounds__(128) void k_head(const float* __restrict__ h,
                                              const float* __restrict__ nw,
                                              const float* __restrict__ opw,
                                              const float* __restrict__ opb,
                                              float* __restrict__ out) {
    __shared__ float red[4];
    int b = blockIdx.x, d = threadIdx.x;
    float hv = h[((size_t)b*L_ + (L_-1))*DM + d];
    float v = hv * hv;
    for (int off = 1; off < 64; off <<= 1) v += __shfl_xor(v, off);
    if ((d & 63) == 0) red[d >> 6] = v;
    __syncthreads();
    float ss = red[0] + red[1];
    float rms = sqrtf(ss * (1.f/DM) + 1e-6f);
    float hn = nw[d] * hv / rms;
    float pv = hn * opw[d];
    for (int off = 1; off < 64; off <<= 1) pv += __shfl_xor(pv, off);
    if ((d & 63) == 0) red[2 + (d >> 6)] = pv;
    __syncthreads();
    if (d == 0) out[b] = red[2] + red[3] + opb[0];
}

extern "C" void kernel_launch(void* const* d_in, const int* in_sizes, int n_in,
                              void* d_out, int out_size, void* d_ws, size_t ws_size,
                              hipStream_t stream) {
    (void)in_sizes; (void)n_in; (void)out_size;
    float* out = (float*)d_out;

    // ---- canonical arena ----
    char* wp = (char*)d_ws;
    int* flag = (int*)wp; wp += 16;
    auto allocf = [&](size_t elems) {
        float* p = (float*)wp;
        wp += (elems * 4 + 15) & ~(size_t)15;
        return p;
    };
    auto alloch = [&](size_t elems) {
        unsigned short* p = (unsigned short*)wp;
        wp += (elems * 2 + 15) & ~(size_t)15;
        return p;
    };
    float* c_ipw  = allocf(DM);
    float* c_ipb  = allocf(DM);
    float* c_cw   = allocf((size_t)NL*DI*4);
    float* c_cb   = allocf((size_t)NL*DI);
    float* c_dtw  = allocf((size_t)NL*DI*RANK);
    float* c_dtb  = allocf((size_t)NL*DI);
    float* c_alog = allocf((size_t)NL*DI*DS_);
    float* c_D    = allocf((size_t)NL*DI);
    float* c_nw   = allocf(DM);
    float* c_opw  = allocf(DM);
    float* c_opb  = allocf(1);
    unsigned short* c_inw16 = alloch((size_t)NL*2*DI*DM);
    unsigned short* c_ow16  = alloch((size_t)NL*DM*DI);
    unsigned short* c_xpw48 = alloch((size_t)NL*48*DI);
    wp = (char*)(((size_t)wp + 255) & ~(size_t)255);

    k_detect<<<1, 256, 0, stream>>>((const unsigned short*)d_in[0], flag);

    CvtPack pk;
    pk.seg[0]  = { d_in[1],  c_ipw,  DM };
    pk.seg[1]  = { d_in[2],  c_ipb,  DM };
    pk.seg[2]  = { d_in[4],  c_cw,   NL*DI*4 };
    pk.seg[3]  = { d_in[5],  c_cb,   NL*DI };
    pk.seg[4]  = { d_in[7],  c_dtw,  NL*DI*RANK };
    pk.seg[5]  = { d_in[8],  c_dtb,  NL*DI };
    pk.seg[6]  = { d_in[9],  c_alog, NL*DI*DS_ };
    pk.seg[7]  = { d_in[10], c_D,    NL*DI };
    pk.seg[8]  = { d_in[12], c_nw,   DM };
    pk.seg[9]  = { d_in[13], c_opw,  DM };
    pk.seg[10] = { d_in[14], c_opb,  1 };
    k_cvt_params<<<dim3(64, 11), 256, 0, stream>>>(pk, flag);
    k_cvt16<<<(int)((NL*2*DI*DM + 255)/256), 256, 0, stream>>>(d_in[3],  c_inw16, NL*2*DI*DM, flag);
    k_cvt16<<<(int)((NL*DM*DI   + 255)/256), 256, 0, stream>>>(d_in[11], c_ow16,  NL*DM*DI,   flag);
    k_xpw48<<<NL*48*DI/256, 256, 0, stream>>>(d_in[6], c_xpw48, flag);

    // ---- workspace-adaptive batch chunking over remaining ws ----
    // per-row: h 512 + xb/yg 512 + zb 512 + xcg 512 + ylg 512 + Sg 512 + C 32 = 3104 B
    size_t used  = (size_t)(wp - (char*)d_ws);
    size_t avail = (ws_size > used) ? ws_size - used : 0;
    const size_t perB = (size_t)L_ * 3104 + (size_t)2 * NC * DI * DS_ * 2;
    int cb = B_;
    while (cb > 1 && (size_t)cb * perB > avail) cb >>= 1;
    const int Mc = cb * L_;

    float* h            = (float*)wp;          wp += (size_t)Mc*DM*4;
    unsigned short* xb  = (unsigned short*)wp; wp += (size_t)Mc*DI*2;   // pre-conv x, later yg
    unsigned short* zb  = (unsigned short*)wp; wp += (size_t)Mc*DI*2;
    unsigned short* xcg = (unsigned short*)wp; wp += (size_t)Mc*DI*2;   // bf16 conv output
    unsigned short* ylg = (unsigned short*)wp; wp += (size_t)Mc*DI*2;   // bf16 y_loc
    unsigned short* Sg  = (unsigned short*)wp; wp += (size_t)Mc*DI*2;   // bf16 prefix dt
    unsigned short* Cg  = (unsigned short*)wp; wp += (size_t)Mc*DS_*2;  // bf16 C
    unsigned short* Pbuf = (unsigned short*)wp; wp += (size_t)cb*NC*DI*DS_*2;  // bf16
    unsigned short* Hbuf = (unsigned short*)wp; wp += (size_t)cb*NC*DI*DS_*2;  // bf16

    const int scan2_blocks = (cb * DI * DS_ + 255) / 256;

    for (int b0 = 0; b0 < B_; b0 += cb) {
        k_init<<<Mc*DM/256, 256, 0, stream>>>(d_in[0], flag, c_ipw, c_ipb, h, b0*L_);
        k_gemm_in<<<dim3(Mc/64, 2), 256, 0, stream>>>(h, c_inw16, xb, zb);   // layer 0
        for (int i = 0; i < NL; ++i) {
            k_xprojc<<<Mc/64, 256, 0, stream>>>(xb, c_cw + i*DI*4, c_cb + i*DI,
                                                c_xpw48 + (size_t)i*48*DI,
                                                c_dtw + i*DI*RANK, c_dtb + i*DI,
                                                c_alog + i*DI*DS_,
                                                xcg, ylg, Sg, Cg, Pbuf, Hbuf);
            k_scan2<<<scan2_blocks, 256, 0, stream>>>(Pbuf, Hbuf, cb);
            k_ygate<<<dim3(NC, cb), 256, 0, stream>>>(ylg, Sg, xcg, Cg, c_alog + i*DI*DS_,
                                                      Hbuf, zb, c_D + i*DI, xb);
            if (i < NL-1)
                k_gemm_oi<<<Mc/64, 256, 0, stream>>>(xb, c_ow16 + (size_t)i*DM*DI,
                                                     c_inw16 + (size_t)(i+1)*2*DI*DM,
                                                     h, xb, zb);
            else
                k_gemm_out<<<Mc/64, 256, 0, stream>>>(xb, c_ow16 + (size_t)i*DM*DI, h);
        }
        k_head<<<cb, 128, 0, stream>>>(h, c_nw, c_opw, c_opb, out + b0);
    }
}